// Round 1
// baseline (734.645 us; speedup 1.0000x reference)
//
#include <hip/hip_runtime.h>

#define NN 50000
#define NE 800000
#define DIM 128
#define NB 1024
#define CTXL 50
#define BN_EPS 1e-5f

// ---------------- ws layout (float offsets) ----------------
// agg/z     : 0          .. 6,400,000
// col_s     : 6,400,000  (800,000 ints)
// norm_s    : 7,200,000  (800,000 floats)
// row_start : 8,000,000  (50,001 ints)
// cursor    : 8,050,048  (50,000 ints)
// counts    : 8,100,096  (50,000 ints)
// stats     : 8,150,144  (256 floats: sum[128], sumsq[128])
// scsh      : 8,150,400  (256 floats: scale[128], shift[128])
static const size_t OFF_COL   = 6400000;
static const size_t OFF_NRM   = 7200000;
static const size_t OFF_RS    = 8000000;
static const size_t OFF_CUR   = 8050048;
static const size_t OFF_CNT   = 8100096;
static const size_t OFF_STATS = 8150144;
static const size_t OFF_SCSH  = 8150400;

// ---------------- CSR build ----------------
__global__ void hist_kernel(const int* __restrict__ row, int* __restrict__ counts) {
    int e = blockIdx.x * 256 + threadIdx.x;
    if (e < NE) atomicAdd(&counts[row[e]], 1);
}

__global__ __launch_bounds__(1024) void scan_kernel(const int* __restrict__ counts,
                                                    int* __restrict__ row_start,
                                                    int* __restrict__ cursor) {
    __shared__ int lds[1024];
    const int CHUNK = 49;  // 1024*49 = 50176 >= 50000
    int t = threadIdx.x;
    int base = t * CHUNK;
    int s = 0;
    for (int i = 0; i < CHUNK; i++) {
        int idx = base + i;
        if (idx < NN) s += counts[idx];
    }
    lds[t] = s;
    __syncthreads();
    for (int off = 1; off < 1024; off <<= 1) {
        int v = lds[t];
        int add = (t >= off) ? lds[t - off] : 0;
        __syncthreads();
        lds[t] = v + add;
        __syncthreads();
    }
    int run = (t == 0) ? 0 : lds[t - 1];
    for (int i = 0; i < CHUNK; i++) {
        int idx = base + i;
        if (idx < NN) {
            row_start[idx] = run;
            cursor[idx] = run;
            run += counts[idx];
        }
    }
    if (t == 1023) row_start[NN] = lds[1023];
}

__global__ void scatter_kernel(const int* __restrict__ row, const int* __restrict__ col,
                               const float* __restrict__ norm, int* __restrict__ cursor,
                               int* __restrict__ col_s, float* __restrict__ norm_s) {
    int e = blockIdx.x * 256 + threadIdx.x;
    if (e < NE) {
        int r = row[e];
        int p = atomicAdd(&cursor[r], 1);
        col_s[p] = col[e];
        norm_s[p] = norm[e];
    }
}

// ---------------- aggregation: one wave per destination row ----------------
__global__ __launch_bounds__(256) void agg_kernel(const float* __restrict__ h,
                                                  const int* __restrict__ row_start,
                                                  const int* __restrict__ col_s,
                                                  const float* __restrict__ norm_s,
                                                  float* __restrict__ agg) {
    int gw = (blockIdx.x * 256 + threadIdx.x) >> 6;
    int lane = threadIdx.x & 63;
    if (gw >= NN) return;
    int s = row_start[gw];
    int e = row_start[gw + 1];
    float2 acc = make_float2(0.f, 0.f);
    for (int j = s; j < e; j++) {
        int c = col_s[j];
        float w = norm_s[j];
        float2 hv = *reinterpret_cast<const float2*>(h + (size_t)c * DIM + lane * 2);
        acc.x += w * hv.x;
        acc.y += w * hv.y;
    }
    *reinterpret_cast<float2*>(agg + (size_t)gw * DIM + lane * 2) = acc;
}

// ---------------- z = relu(agg @ W^T), fused BN partial sums ----------------
// Wt LDS layout (XOR-swizzled to kill 32-way bank conflicts):
//   Wt[k*64 + (c2 ^ (k&63))] = (W[2*c2][k], W[2*c2+1][k])
__global__ __launch_bounds__(256) void gemm_bn_kernel(const float* a_in,
                                                      float* z_out,
                                                      const float* __restrict__ W,
                                                      float* __restrict__ stats) {
    __shared__ __align__(16) float2 Wt[8192];  // 64 KB
    int tid = threadIdx.x;
    for (int f = tid; f < 8192; f += 256) {
        int k = f & 127;
        int c2 = f >> 7;
        float v0 = W[(2 * c2) * 128 + k];
        float v1 = W[(2 * c2 + 1) * 128 + k];
        Wt[k * 64 + (c2 ^ (k & 63))] = make_float2(v0, v1);
    }
    __syncthreads();
    int lane = tid & 63;
    int gw = blockIdx.x * 4 + (tid >> 6);
    int nw = gridDim.x * 4;
    float2 sum = make_float2(0.f, 0.f);
    float2 sq = make_float2(0.f, 0.f);
    for (int r = gw; r < NN; r += nw) {
        float2 a = *reinterpret_cast<const float2*>(a_in + (size_t)r * DIM + lane * 2);
        float zx = 0.f, zy = 0.f;
        #pragma unroll 16
        for (int k2 = 0; k2 < 64; k2++) {
            float ax = __shfl(a.x, k2);
            float ay = __shfl(a.y, k2);
            int k0 = 2 * k2;
            int k1 = 2 * k2 + 1;
            float2 w0 = Wt[k0 * 64 + (lane ^ (k0 & 63))];
            float2 w1 = Wt[k1 * 64 + (lane ^ (k1 & 63))];
            zx += ax * w0.x + ay * w1.x;
            zy += ax * w0.y + ay * w1.y;
        }
        zx = fmaxf(zx, 0.f);
        zy = fmaxf(zy, 0.f);
        sum.x += zx; sum.y += zy;
        sq.x += zx * zx; sq.y += zy * zy;
        *reinterpret_cast<float2*>(z_out + (size_t)r * DIM + lane * 2) = make_float2(zx, zy);
    }
    __syncthreads();
    float4* red = reinterpret_cast<float4*>(Wt);
    red[tid] = make_float4(sum.x, sum.y, sq.x, sq.y);
    __syncthreads();
    if (tid < 64) {
        float4 r0 = red[tid], r1 = red[tid + 64], r2 = red[tid + 128], r3 = red[tid + 192];
        unsafeAtomicAdd(&stats[2 * tid],       r0.x + r1.x + r2.x + r3.x);
        unsafeAtomicAdd(&stats[2 * tid + 1],   r0.y + r1.y + r2.y + r3.y);
        unsafeAtomicAdd(&stats[128 + 2 * tid],     r0.z + r1.z + r2.z + r3.z);
        unsafeAtomicAdd(&stats[128 + 2 * tid + 1], r0.w + r1.w + r2.w + r3.w);
    }
}

__global__ void bn_finalize_kernel(float* __restrict__ stats, const float* __restrict__ gamma,
                                   const float* __restrict__ beta, float* __restrict__ scsh) {
    int c = threadIdx.x;
    if (c < 128) {
        float mu = stats[c] * (1.f / (float)NN);
        float ex2 = stats[128 + c] * (1.f / (float)NN);
        float var = ex2 - mu * mu;
        float sc = gamma[c] / sqrtf(var + BN_EPS);
        scsh[c] = sc;
        scsh[128 + c] = beta[c] - mu * sc;
        stats[c] = 0.f;        // reset for next layer / next call
        stats[128 + c] = 0.f;
    }
}

// ---------------- h_out = h_in + z*scale + shift ----------------
__global__ __launch_bounds__(256) void residual_kernel(const float* hin,
                                                       const float* z,
                                                       const float* __restrict__ scsh,
                                                       float* hout) {
    int i = blockIdx.x * 256 + threadIdx.x;  // float4 index
    if (i >= NN * DIM / 4) return;
    int c = (i * 4) & 127;
    float4 zv = reinterpret_cast<const float4*>(z)[i];
    float4 hv = reinterpret_cast<const float4*>(hin)[i];
    float4 sc = *reinterpret_cast<const float4*>(scsh + c);
    float4 sh = *reinterpret_cast<const float4*>(scsh + 128 + c);
    float4 o;
    o.x = hv.x + zv.x * sc.x + sh.x;
    o.y = hv.y + zv.y * sc.y + sh.y;
    o.z = hv.z + zv.z * sc.z + sh.z;
    o.w = hv.w + zv.w * sc.w + sh.w;
    reinterpret_cast<float4*>(hout)[i] = o;
}

// ---------------- fused batch head: attention pool + fusion + MLP ----------------
__global__ __launch_bounds__(256) void batch_kernel(const int* __restrict__ ctx_ids,
                                                    const int* __restrict__ miss_ids,
                                                    const int* __restrict__ vocab_to_fg,
                                                    const float* __restrict__ emb_table,
                                                    const float* __restrict__ graph,
                                                    const float* __restrict__ attn_w,
                                                    const float* __restrict__ attn_b,
                                                    const float* __restrict__ fusion_w,
                                                    const float* __restrict__ fusion_b,
                                                    const float* __restrict__ proj1_w,
                                                    const float* __restrict__ proj1_b,
                                                    const float* __restrict__ proj2_w,
                                                    const float* __restrict__ proj2_b,
                                                    float* __restrict__ query) {
    int b = blockIdx.x;
    int tid = threadIdx.x;
    __shared__ float ctx[CTXL][129];  // +1 pad: kills 50-way bank conflict in logit dot
    __shared__ float aw[128];
    __shared__ float lg[64];
    __shared__ __align__(16) float qin[256];
    __shared__ __align__(16) float cat[256];
    __shared__ __align__(16) float q1[256];

    if (tid < 128) aw[tid] = attn_w[tid];
    for (int f = tid; f < CTXL * 128; f += 256) {
        int t = f >> 7, d = f & 127;
        int vid = ctx_ids[b * CTXL + t];
        ctx[t][d] = emb_table[(size_t)vid * DIM + d];
    }
    __syncthreads();

    if (tid < CTXL) {
        float s = 0.f;
        for (int k = 0; k < 128; k++) s += ctx[tid][k] * aw[k];
        lg[tid] = s + attn_b[0];
    }
    __syncthreads();

    if (tid < 64) {
        float v = (tid < CTXL) ? lg[tid] : -INFINITY;
        float m = v;
        for (int off = 32; off; off >>= 1) m = fmaxf(m, __shfl_xor(m, off));
        float e = (tid < CTXL) ? expf(v - m) : 0.f;
        float s = e;
        for (int off = 32; off; off >>= 1) s += __shfl_xor(s, off);
        if (tid < CTXL) lg[tid] = e / s;
    }
    __syncthreads();

    // ctx_emb -> qin[0:128]
    if (tid < 128) {
        float s = 0.f;
        for (int t = 0; t < CTXL; t++) s += lg[t] * ctx[t][tid];
        qin[tid] = s;
    }
    // cat = [base, gp]
    int mid = miss_ids[b];
    if (tid < 128) {
        cat[tid] = emb_table[(size_t)mid * DIM + tid];
    } else {
        int d = tid - 128;
        int fg = vocab_to_fg[mid];
        cat[tid] = (fg >= 0) ? graph[(size_t)fg * DIM + d] : 0.f;
    }
    __syncthreads();

    // miss_emb -> qin[128:256]
    if (tid < 128) {
        float s = fusion_b[tid];
        const float4* wr = reinterpret_cast<const float4*>(fusion_w + (size_t)tid * 256);
        const float4* cr = reinterpret_cast<const float4*>(cat);
        for (int k = 0; k < 64; k++) {
            float4 w4 = wr[k];
            float4 c4 = cr[k];
            s += w4.x * c4.x + w4.y * c4.y + w4.z * c4.z + w4.w * c4.w;
        }
        qin[128 + tid] = s;
    }
    __syncthreads();

    // proj1 + relu
    {
        float s = proj1_b[tid];
        const float4* wr = reinterpret_cast<const float4*>(proj1_w + (size_t)tid * 256);
        const float4* cr = reinterpret_cast<const float4*>(qin);
        for (int k = 0; k < 64; k++) {
            float4 w4 = wr[k];
            float4 c4 = cr[k];
            s += w4.x * c4.x + w4.y * c4.y + w4.z * c4.z + w4.w * c4.w;
        }
        q1[tid] = fmaxf(s, 0.f);
    }
    __syncthreads();

    // proj2 -> query
    if (tid < 128) {
        float s = proj2_b[tid];
        const float4* wr = reinterpret_cast<const float4*>(proj2_w + (size_t)tid * 256);
        const float4* cr = reinterpret_cast<const float4*>(q1);
        for (int k = 0; k < 64; k++) {
            float4 w4 = wr[k];
            float4 c4 = cr[k];
            s += w4.x * c4.x + w4.y * c4.y + w4.z * c4.z + w4.w * c4.w;
        }
        query[(size_t)b * DIM + tid] = s;
    }
}

extern "C" void kernel_launch(void* const* d_in, const int* in_sizes, int n_in,
                              void* d_out, int out_size, void* d_ws, size_t ws_size,
                              hipStream_t stream) {
    const int*   edge_index = (const int*)d_in[0];
    const float* norm       = (const float*)d_in[1];
    const int*   ctx_ids    = (const int*)d_in[2];
    const int*   miss_ids   = (const int*)d_in[3];
    const int*   vocab_to_fg= (const int*)d_in[4];
    const float* emb_table  = (const float*)d_in[5];
    const float* fg_emb     = (const float*)d_in[6];
    const float* gc_w       = (const float*)d_in[7];
    const float* bn_gamma   = (const float*)d_in[8];
    const float* bn_beta    = (const float*)d_in[9];
    const float* attn_w     = (const float*)d_in[10];
    const float* attn_b     = (const float*)d_in[11];
    const float* fusion_w   = (const float*)d_in[12];
    const float* fusion_b   = (const float*)d_in[13];
    const float* proj1_w    = (const float*)d_in[14];
    const float* proj1_b    = (const float*)d_in[15];
    const float* proj2_w    = (const float*)d_in[16];
    const float* proj2_b    = (const float*)d_in[17];

    const int* row = edge_index;
    const int* col = edge_index + NE;

    float* ws = (float*)d_ws;
    float* agg      = ws;
    int*   col_s    = (int*)(ws + OFF_COL);
    float* norm_s   = ws + OFF_NRM;
    int*   row_start= (int*)(ws + OFF_RS);
    int*   cursor   = (int*)(ws + OFF_CUR);
    int*   counts   = (int*)(ws + OFF_CNT);
    float* stats    = ws + OFF_STATS;
    float* scsh     = ws + OFF_SCSH;

    float* query = (float*)d_out;
    float* G     = (float*)d_out + (size_t)NB * DIM;  // graph_embs region, doubles as h

    hipMemsetAsync(counts, 0, NN * sizeof(int), stream);
    hipMemsetAsync(stats, 0, 256 * sizeof(float), stream);

    const int EB = (NE + 255) / 256;  // 3125
    hist_kernel<<<EB, 256, 0, stream>>>(row, counts);
    scan_kernel<<<1, 1024, 0, stream>>>(counts, row_start, cursor);
    scatter_kernel<<<EB, 256, 0, stream>>>(row, col, norm, cursor, col_s, norm_s);

    const int AGG_B = NN / 4;          // 12500 blocks, one wave per row
    const int RES_B = (NN * DIM / 4) / 256;  // 6250

    // ---- layer 1: h1 = fg_emb + BN(relu(agg(fg_emb) @ W0^T)) -> G ----
    agg_kernel<<<AGG_B, 256, 0, stream>>>(fg_emb, row_start, col_s, norm_s, agg);
    gemm_bn_kernel<<<512, 256, 0, stream>>>(agg, agg, gc_w, stats);
    bn_finalize_kernel<<<1, 128, 0, stream>>>(stats, bn_gamma, bn_beta, scsh);
    residual_kernel<<<RES_B, 256, 0, stream>>>(fg_emb, agg, scsh, G);

    // ---- layer 2: G = G + BN(relu(agg(G) @ W1^T)) in-place ----
    agg_kernel<<<AGG_B, 256, 0, stream>>>(G, row_start, col_s, norm_s, agg);
    gemm_bn_kernel<<<512, 256, 0, stream>>>(agg, agg, gc_w + 128 * 128, stats);
    bn_finalize_kernel<<<1, 128, 0, stream>>>(stats, bn_gamma + 128, bn_beta + 128, scsh);
    residual_kernel<<<RES_B, 256, 0, stream>>>(G, agg, scsh, G);

    // ---- batch head ----
    batch_kernel<<<NB, 256, 0, stream>>>(ctx_ids, miss_ids, vocab_to_fg, emb_table, G,
                                         attn_w, attn_b, fusion_w, fusion_b,
                                         proj1_w, proj1_b, proj2_w, proj2_b, query);
}